// Round 2
// baseline (1413.819 us; speedup 1.0000x reference)
//
#include <hip/hip_runtime.h>

typedef unsigned short u16;
typedef unsigned int u32;
typedef __attribute__((ext_vector_type(8))) __bf16 bf16x8;
typedef __attribute__((ext_vector_type(4))) float f32x4;
typedef __attribute__((ext_vector_type(2))) u32 u32x2;
typedef __attribute__((ext_vector_type(4))) u32 u32x4;

__device__ __forceinline__ u16 f2bf(float f) {
    u32 u = __float_as_uint(f);
    u = (u + 0x7FFFu + ((u >> 16) & 1u)) >> 16;
    return (u16)u;
}

__device__ __forceinline__ bf16x8 load8f_bf(const float* p) {
    f32x4 f0 = *(const f32x4*)p;
    f32x4 f1 = *(const f32x4*)(p + 4);
    u32x4 q;
    q[0] = (u32)f2bf(f0[0]) | ((u32)f2bf(f0[1]) << 16);
    q[1] = (u32)f2bf(f0[2]) | ((u32)f2bf(f0[3]) << 16);
    q[2] = (u32)f2bf(f1[0]) | ((u32)f2bf(f1[1]) << 16);
    q[3] = (u32)f2bf(f1[2]) | ((u32)f2bf(f1[3]) << 16);
    return __builtin_bit_cast(bf16x8, q);
}

// packed A-fragment (W^T) layout, per layer: idx = ((s*4 + m)*64 + lane)*8 + j
// value = W[k][16*m + (lane&15)], k = s*32 + (lane>>4)*8 + j
// (A/B share the same per-lane k-map, so any consistent bijection is correct.)
#define PK_EW1 0
#define PK_EW2 12288
#define PK_EW3 16384
#define PK_NW1 20480
#define PK_NW2 28672
#define PK_NW3 32768
#define PK_TOTAL 36864

__global__ void pack_weights_kernel(const float* __restrict__ eW1, const float* __restrict__ eW2,
                                    const float* __restrict__ eW3, const float* __restrict__ nW1,
                                    const float* __restrict__ nW2, const float* __restrict__ nW3,
                                    u16* __restrict__ P) {
    int idx = blockIdx.x * blockDim.x + threadIdx.x;
    if (idx >= PK_TOTAL) return;
    const float* W; int base;
    if (idx < PK_EW2)      { W = eW1; base = PK_EW1; }
    else if (idx < PK_EW3) { W = eW2; base = PK_EW2; }
    else if (idx < PK_NW1) { W = eW3; base = PK_EW3; }
    else if (idx < PK_NW2) { W = nW1; base = PK_NW1; }
    else if (idx < PK_NW3) { W = nW2; base = PK_NW2; }
    else                   { W = nW3; base = PK_NW3; }
    int r = idx - base;
    int j = r & 7, lane = (r >> 3) & 63, m = (r >> 9) & 3, s = r >> 11;
    int k = s * 32 + (lane >> 4) * 8 + j;
    int col = 16 * m + (lane & 15);
    P[idx] = f2bf(W[k * 64 + col]);
}

// ---------------- edge MLP + LN + scatter-add ----------------
__global__ __launch_bounds__(256) void edge_mlp_kernel(
    const float* __restrict__ node_feat, const float* __restrict__ edge_feat,
    const int* __restrict__ edge_idx, const u16* __restrict__ Pw,
    const float* __restrict__ b1g, const float* __restrict__ b2g, const float* __restrict__ b3g,
    const float* __restrict__ gg, const float* __restrict__ betag,
    float* __restrict__ nodal, float* __restrict__ out_edge, int E)
{
    __shared__ float params[5][64];
    __shared__ u16 htile[4][1024];  // per-wave 16x64 bf16 tile, XOR-swizzled
    const int tid = threadIdx.x;
    if (tid < 64) {
        params[0][tid] = b1g[tid];
        params[1][tid] = b2g[tid];
        params[2][tid] = b3g[tid];
        params[3][tid] = gg[tid];
        params[4][tid] = betag[tid];
    }
    __syncthreads();
    const int wid = tid >> 6, lane = tid & 63;
    const int er = lane & 15, a = lane >> 4;
    const int ebase = (blockIdx.x * 4 + wid) * 16;
    if (ebase >= E) return;
    const int e = ebase + er;
    const int cn = edge_idx[2 * e];
    const int sn = edge_idx[2 * e + 1];
    u16* ht = htile[wid];
    const int swz = (er & 7) << 4;

    f32x4 acc[4];
#pragma unroll
    for (int m = 0; m < 4; ++m) acc[m] = 0.0f;

    // ---- layer 1: K = 192 (concat: edge_feat | node_feat[center] | node_feat[source])
#pragma unroll
    for (int s = 0; s < 6; ++s) {
        const float* src;
        if (s < 2)      src = edge_feat + (size_t)e * 64 + s * 32 + a * 8;
        else if (s < 4) src = node_feat + (size_t)cn * 64 + (s - 2) * 32 + a * 8;
        else            src = node_feat + (size_t)sn * 64 + (s - 4) * 32 + a * 8;
        bf16x8 bf = load8f_bf(src);
#pragma unroll
        for (int m = 0; m < 4; ++m) {
            bf16x8 af = *(const bf16x8*)(Pw + PK_EW1 + ((s * 4 + m) * 64 + lane) * 8);
            acc[m] = __builtin_amdgcn_mfma_f32_16x16x32_bf16(af, bf, acc[m], 0, 0, 0);
        }
    }
    // bias + relu -> htile (bf16)
#pragma unroll
    for (int m = 0; m < 4; ++m) {
        float v0 = fmaxf(acc[m][0] + params[0][16 * m + 4 * a + 0], 0.0f);
        float v1 = fmaxf(acc[m][1] + params[0][16 * m + 4 * a + 1], 0.0f);
        float v2 = fmaxf(acc[m][2] + params[0][16 * m + 4 * a + 2], 0.0f);
        float v3 = fmaxf(acc[m][3] + params[0][16 * m + 4 * a + 3], 0.0f);
        u32x2 pv;
        pv[0] = (u32)f2bf(v0) | ((u32)f2bf(v1) << 16);
        pv[1] = (u32)f2bf(v2) | ((u32)f2bf(v3) << 16);
        int boff = (er * 128 + (16 * m + 4 * a) * 2) ^ swz;
        *(u32x2*)((char*)ht + boff) = pv;
    }

    // ---- layer 2: K = 64
#pragma unroll
    for (int m = 0; m < 4; ++m) acc[m] = 0.0f;
#pragma unroll
    for (int s = 0; s < 2; ++s) {
        int boff = (er * 128 + s * 64 + a * 16) ^ swz;
        bf16x8 bf = *(const bf16x8*)((char*)ht + boff);
#pragma unroll
        for (int m = 0; m < 4; ++m) {
            bf16x8 af = *(const bf16x8*)(Pw + PK_EW2 + ((s * 4 + m) * 64 + lane) * 8);
            acc[m] = __builtin_amdgcn_mfma_f32_16x16x32_bf16(af, bf, acc[m], 0, 0, 0);
        }
    }
#pragma unroll
    for (int m = 0; m < 4; ++m) {
        float v0 = fmaxf(acc[m][0] + params[1][16 * m + 4 * a + 0], 0.0f);
        float v1 = fmaxf(acc[m][1] + params[1][16 * m + 4 * a + 1], 0.0f);
        float v2 = fmaxf(acc[m][2] + params[1][16 * m + 4 * a + 2], 0.0f);
        float v3 = fmaxf(acc[m][3] + params[1][16 * m + 4 * a + 3], 0.0f);
        u32x2 pv;
        pv[0] = (u32)f2bf(v0) | ((u32)f2bf(v1) << 16);
        pv[1] = (u32)f2bf(v2) | ((u32)f2bf(v3) << 16);
        int boff = (er * 128 + (16 * m + 4 * a) * 2) ^ swz;
        *(u32x2*)((char*)ht + boff) = pv;
    }

    // ---- layer 3: K = 64 (no relu), then LayerNorm
#pragma unroll
    for (int m = 0; m < 4; ++m) acc[m] = 0.0f;
#pragma unroll
    for (int s = 0; s < 2; ++s) {
        int boff = (er * 128 + s * 64 + a * 16) ^ swz;
        bf16x8 bf = *(const bf16x8*)((char*)ht + boff);
#pragma unroll
        for (int m = 0; m < 4; ++m) {
            bf16x8 af = *(const bf16x8*)(Pw + PK_EW3 + ((s * 4 + m) * 64 + lane) * 8);
            acc[m] = __builtin_amdgcn_mfma_f32_16x16x32_bf16(af, bf, acc[m], 0, 0, 0);
        }
    }
    float vals[16], sum = 0.0f, ssq = 0.0f;
#pragma unroll
    for (int m = 0; m < 4; ++m)
#pragma unroll
        for (int r = 0; r < 4; ++r) {
            float v = acc[m][r] + params[2][16 * m + 4 * a + r];
            vals[4 * m + r] = v; sum += v; ssq += v * v;
        }
    sum += __shfl_xor(sum, 16, 64); sum += __shfl_xor(sum, 32, 64);
    ssq += __shfl_xor(ssq, 16, 64); ssq += __shfl_xor(ssq, 32, 64);
    const float mean = sum * 0.015625f;
    const float var = ssq * 0.015625f - mean * mean;
    const float inv = rsqrtf(var + 1e-5f);
    float* nrow = nodal + (size_t)cn * 64;
#pragma unroll
    for (int m = 0; m < 4; ++m) {
        f32x4 o;
#pragma unroll
        for (int r = 0; r < 4; ++r) {
            int f = 16 * m + 4 * a + r;
            float ov = (vals[4 * m + r] - mean) * inv * params[3][f] + params[4][f];
            o[r] = ov;
            unsafeAtomicAdd(nrow + f, ov);   // fp32 segment_sum
        }
        *(f32x4*)(out_edge + (size_t)e * 64 + 16 * m + 4 * a) = o;
    }
}

// ---------------- node MLP + LN ----------------
__global__ __launch_bounds__(256) void node_mlp_kernel(
    const float* __restrict__ node_feat, const float* __restrict__ nodal,
    const u16* __restrict__ Pw,
    const float* __restrict__ b1g, const float* __restrict__ b2g, const float* __restrict__ b3g,
    const float* __restrict__ gg, const float* __restrict__ betag,
    float* __restrict__ out_node, int N)
{
    __shared__ float params[5][64];
    __shared__ u16 htile[4][1024];
    const int tid = threadIdx.x;
    if (tid < 64) {
        params[0][tid] = b1g[tid];
        params[1][tid] = b2g[tid];
        params[2][tid] = b3g[tid];
        params[3][tid] = gg[tid];
        params[4][tid] = betag[tid];
    }
    __syncthreads();
    const int wid = tid >> 6, lane = tid & 63;
    const int er = lane & 15, a = lane >> 4;
    const int nbase = (blockIdx.x * 4 + wid) * 16;
    if (nbase >= N) return;
    const int n = nbase + er;
    u16* ht = htile[wid];
    const int swz = (er & 7) << 4;

    f32x4 acc[4];
#pragma unroll
    for (int m = 0; m < 4; ++m) acc[m] = 0.0f;

    // ---- layer 1: K = 128 (concat: node_feat | nodal_edge_feat)
#pragma unroll
    for (int s = 0; s < 4; ++s) {
        const float* src = (s < 2) ? (node_feat + (size_t)n * 64 + s * 32 + a * 8)
                                   : (nodal + (size_t)n * 64 + (s - 2) * 32 + a * 8);
        bf16x8 bf = load8f_bf(src);
#pragma unroll
        for (int m = 0; m < 4; ++m) {
            bf16x8 af = *(const bf16x8*)(Pw + PK_NW1 + ((s * 4 + m) * 64 + lane) * 8);
            acc[m] = __builtin_amdgcn_mfma_f32_16x16x32_bf16(af, bf, acc[m], 0, 0, 0);
        }
    }
#pragma unroll
    for (int m = 0; m < 4; ++m) {
        float v0 = fmaxf(acc[m][0] + params[0][16 * m + 4 * a + 0], 0.0f);
        float v1 = fmaxf(acc[m][1] + params[0][16 * m + 4 * a + 1], 0.0f);
        float v2 = fmaxf(acc[m][2] + params[0][16 * m + 4 * a + 2], 0.0f);
        float v3 = fmaxf(acc[m][3] + params[0][16 * m + 4 * a + 3], 0.0f);
        u32x2 pv;
        pv[0] = (u32)f2bf(v0) | ((u32)f2bf(v1) << 16);
        pv[1] = (u32)f2bf(v2) | ((u32)f2bf(v3) << 16);
        int boff = (er * 128 + (16 * m + 4 * a) * 2) ^ swz;
        *(u32x2*)((char*)ht + boff) = pv;
    }

    // ---- layer 2
#pragma unroll
    for (int m = 0; m < 4; ++m) acc[m] = 0.0f;
#pragma unroll
    for (int s = 0; s < 2; ++s) {
        int boff = (er * 128 + s * 64 + a * 16) ^ swz;
        bf16x8 bf = *(const bf16x8*)((char*)ht + boff);
#pragma unroll
        for (int m = 0; m < 4; ++m) {
            bf16x8 af = *(const bf16x8*)(Pw + PK_NW2 + ((s * 4 + m) * 64 + lane) * 8);
            acc[m] = __builtin_amdgcn_mfma_f32_16x16x32_bf16(af, bf, acc[m], 0, 0, 0);
        }
    }
#pragma unroll
    for (int m = 0; m < 4; ++m) {
        float v0 = fmaxf(acc[m][0] + params[1][16 * m + 4 * a + 0], 0.0f);
        float v1 = fmaxf(acc[m][1] + params[1][16 * m + 4 * a + 1], 0.0f);
        float v2 = fmaxf(acc[m][2] + params[1][16 * m + 4 * a + 2], 0.0f);
        float v3 = fmaxf(acc[m][3] + params[1][16 * m + 4 * a + 3], 0.0f);
        u32x2 pv;
        pv[0] = (u32)f2bf(v0) | ((u32)f2bf(v1) << 16);
        pv[1] = (u32)f2bf(v2) | ((u32)f2bf(v3) << 16);
        int boff = (er * 128 + (16 * m + 4 * a) * 2) ^ swz;
        *(u32x2*)((char*)ht + boff) = pv;
    }

    // ---- layer 3 + LN
#pragma unroll
    for (int m = 0; m < 4; ++m) acc[m] = 0.0f;
#pragma unroll
    for (int s = 0; s < 2; ++s) {
        int boff = (er * 128 + s * 64 + a * 16) ^ swz;
        bf16x8 bf = *(const bf16x8*)((char*)ht + boff);
#pragma unroll
        for (int m = 0; m < 4; ++m) {
            bf16x8 af = *(const bf16x8*)(Pw + PK_NW3 + ((s * 4 + m) * 64 + lane) * 8);
            acc[m] = __builtin_amdgcn_mfma_f32_16x16x32_bf16(af, bf, acc[m], 0, 0, 0);
        }
    }
    float vals[16], sum = 0.0f, ssq = 0.0f;
#pragma unroll
    for (int m = 0; m < 4; ++m)
#pragma unroll
        for (int r = 0; r < 4; ++r) {
            float v = acc[m][r] + params[2][16 * m + 4 * a + r];
            vals[4 * m + r] = v; sum += v; ssq += v * v;
        }
    sum += __shfl_xor(sum, 16, 64); sum += __shfl_xor(sum, 32, 64);
    ssq += __shfl_xor(ssq, 16, 64); ssq += __shfl_xor(ssq, 32, 64);
    const float mean = sum * 0.015625f;
    const float var = ssq * 0.015625f - mean * mean;
    const float inv = rsqrtf(var + 1e-5f);
#pragma unroll
    for (int m = 0; m < 4; ++m) {
        f32x4 o;
#pragma unroll
        for (int r = 0; r < 4; ++r) {
            int f = 16 * m + 4 * a + r;
            o[r] = (vals[4 * m + r] - mean) * inv * params[3][f] + params[4][f];
        }
        *(f32x4*)(out_node + (size_t)n * 64 + 16 * m + 4 * a) = o;
    }
}

extern "C" void kernel_launch(void* const* d_in, const int* in_sizes, int n_in,
                              void* d_out, int out_size, void* d_ws, size_t ws_size,
                              hipStream_t stream) {
    const float* node_feat = (const float*)d_in[0];
    const float* edge_feat = (const float*)d_in[1];
    const int* edge_idx  = (const int*)d_in[2];
    const float* eW1 = (const float*)d_in[4];
    const float* eb1 = (const float*)d_in[5];
    const float* eW2 = (const float*)d_in[6];
    const float* eb2 = (const float*)d_in[7];
    const float* eW3 = (const float*)d_in[8];
    const float* eb3 = (const float*)d_in[9];
    const float* eg  = (const float*)d_in[10];
    const float* ebt = (const float*)d_in[11];
    const float* nW1 = (const float*)d_in[12];
    const float* nb1 = (const float*)d_in[13];
    const float* nW2 = (const float*)d_in[14];
    const float* nb2 = (const float*)d_in[15];
    const float* nW3 = (const float*)d_in[16];
    const float* nb3 = (const float*)d_in[17];
    const float* ng  = (const float*)d_in[18];
    const float* nbt = (const float*)d_in[19];

    const int N = in_sizes[0] / 64;
    const int E = in_sizes[1] / 64;

    float* nodal = (float*)d_ws;                                    // N*64 fp32 segment sums
    u16* Pw = (u16*)((char*)d_ws + (size_t)N * 64 * sizeof(float)); // packed bf16 weights
    float* out_edge = (float*)d_out;
    float* out_node = out_edge + (size_t)E * 64;

    hipMemsetAsync(nodal, 0, (size_t)N * 64 * sizeof(float), stream);
    pack_weights_kernel<<<(PK_TOTAL + 255) / 256, 256, 0, stream>>>(eW1, eW2, eW3, nW1, nW2, nW3, Pw);

    const int eblocks = (E + 63) / 64;
    edge_mlp_kernel<<<eblocks, 256, 0, stream>>>(node_feat, edge_feat, edge_idx, Pw,
                                                 eb1, eb2, eb3, eg, ebt, nodal, out_edge, E);
    const int nblocks = (N + 63) / 64;
    node_mlp_kernel<<<nblocks, 256, 0, stream>>>(node_feat, nodal, Pw,
                                                 nb1, nb2, nb3, ng, nbt, out_node, N);
}

// Round 3
// 700.089 us; speedup vs baseline: 2.0195x; 2.0195x over previous
//
#include <hip/hip_runtime.h>

typedef unsigned short u16;
typedef unsigned int u32;
typedef __attribute__((ext_vector_type(8))) __bf16 bf16x8;
typedef __attribute__((ext_vector_type(4))) float f32x4;
typedef __attribute__((ext_vector_type(2))) u32 u32x2;
typedef __attribute__((ext_vector_type(4))) u32 u32x4;

__device__ __forceinline__ u16 f2bf(float f) {
    u32 u = __float_as_uint(f);
    u = (u + 0x7FFFu + ((u >> 16) & 1u)) >> 16;
    return (u16)u;
}

__device__ __forceinline__ bf16x8 load8f_bf(const float* p) {
    f32x4 f0 = *(const f32x4*)p;
    f32x4 f1 = *(const f32x4*)(p + 4);
    u32x4 q;
    q[0] = (u32)f2bf(f0[0]) | ((u32)f2bf(f0[1]) << 16);
    q[1] = (u32)f2bf(f0[2]) | ((u32)f2bf(f0[3]) << 16);
    q[2] = (u32)f2bf(f1[0]) | ((u32)f2bf(f1[1]) << 16);
    q[3] = (u32)f2bf(f1[2]) | ((u32)f2bf(f1[3]) << 16);
    return __builtin_bit_cast(bf16x8, q);
}

__device__ __forceinline__ bf16x8 cvt2bf(f32x4 lo, f32x4 hi) {
    u32x4 q;
    q[0] = (u32)f2bf(lo[0]) | ((u32)f2bf(lo[1]) << 16);
    q[1] = (u32)f2bf(lo[2]) | ((u32)f2bf(lo[3]) << 16);
    q[2] = (u32)f2bf(hi[0]) | ((u32)f2bf(hi[1]) << 16);
    q[3] = (u32)f2bf(hi[2]) | ((u32)f2bf(hi[3]) << 16);
    return __builtin_bit_cast(bf16x8, q);
}

// packed A-fragment (W^T) layout, per layer: idx = ((s*4 + m)*64 + lane)*8 + j
// value = W[k][16*m + (lane&15)], k = s*32 + (lane>>4)*8 + j
#define PK_EW1 0
#define PK_EW2 12288
#define PK_EW3 16384
#define PK_NW1 20480
#define PK_NW2 28672
#define PK_NW3 32768
#define PK_TOTAL 36864

__global__ void pack_weights_kernel(const float* __restrict__ eW1, const float* __restrict__ eW2,
                                    const float* __restrict__ eW3, const float* __restrict__ nW1,
                                    const float* __restrict__ nW2, const float* __restrict__ nW3,
                                    u16* __restrict__ P) {
    int idx = blockIdx.x * blockDim.x + threadIdx.x;
    if (idx >= PK_TOTAL) return;
    const float* W; int base;
    if (idx < PK_EW2)      { W = eW1; base = PK_EW1; }
    else if (idx < PK_EW3) { W = eW2; base = PK_EW2; }
    else if (idx < PK_NW1) { W = eW3; base = PK_EW3; }
    else if (idx < PK_NW2) { W = nW1; base = PK_NW1; }
    else if (idx < PK_NW3) { W = nW2; base = PK_NW2; }
    else                   { W = nW3; base = PK_NW3; }
    int r = idx - base;
    int j = r & 7, lane = (r >> 3) & 63, m = (r >> 9) & 3, s = r >> 11;
    int k = s * 32 + (lane >> 4) * 8 + j;
    int col = 16 * m + (lane & 15);
    P[idx] = f2bf(W[k * 64 + col]);
}

// ---------------- CSR build: histogram -> scan -> scatter ----------------
__global__ void degree_kernel(const int* __restrict__ edge_idx, int* __restrict__ deg, int E) {
    int e = blockIdx.x * blockDim.x + threadIdx.x;
    if (e < E) atomicAdd(&deg[edge_idx[2 * e]], 1);
}

__global__ void scan_blocks_kernel(const int* __restrict__ deg, int* __restrict__ off,
                                   int* __restrict__ partials, int N) {
    __shared__ int sh[256];
    const int t = threadIdx.x;
    const int g = blockIdx.x * 256 + t;
    int v = (g < N) ? deg[g] : 0;
    sh[t] = v;
    __syncthreads();
#pragma unroll
    for (int d = 1; d < 256; d <<= 1) {
        int add = (t >= d) ? sh[t - d] : 0;
        __syncthreads();
        sh[t] += add;
        __syncthreads();
    }
    if (g < N) off[g] = sh[t] - v;            // exclusive within block
    if (t == 255) partials[blockIdx.x] = sh[255];
}

__global__ void scan_partials_kernel(int* __restrict__ partials, int nparts) {
    __shared__ int sh[256];
    const int t = threadIdx.x;
    int v = (t < nparts) ? partials[t] : 0;
    sh[t] = v;
    __syncthreads();
#pragma unroll
    for (int d = 1; d < 256; d <<= 1) {
        int add = (t >= d) ? sh[t - d] : 0;
        __syncthreads();
        sh[t] += add;
        __syncthreads();
    }
    if (t < nparts) partials[t] = sh[t] - v;  // exclusive
}

__global__ void finalize_offsets_kernel(int* __restrict__ off, int* __restrict__ pos,
                                        const int* __restrict__ partials, int N, int E) {
    int g = blockIdx.x * blockDim.x + threadIdx.x;
    if (g < N) {
        int o = off[g] + partials[g >> 8];
        off[g] = o;
        pos[g] = o;
    }
    if (g == 0) off[N] = E;
}

__global__ void fill_csr_kernel(const int* __restrict__ edge_idx, int* __restrict__ pos,
                                int* __restrict__ csr, int E) {
    int e = blockIdx.x * blockDim.x + threadIdx.x;
    if (e < E) {
        int slot = atomicAdd(&pos[edge_idx[2 * e]], 1);
        csr[slot] = e;
    }
}

// ---------------- edge MLP + LN (no atomics) ----------------
__global__ __launch_bounds__(256) void edge_mlp_kernel(
    const float* __restrict__ node_feat, const float* __restrict__ edge_feat,
    const int* __restrict__ edge_idx, const u16* __restrict__ Pw,
    const float* __restrict__ b1g, const float* __restrict__ b2g, const float* __restrict__ b3g,
    const float* __restrict__ gg, const float* __restrict__ betag,
    float* __restrict__ out_edge, int E)
{
    __shared__ float params[5][64];
    __shared__ u16 htile[4][1024];  // per-wave 16x64 bf16 tile, XOR-swizzled
    const int tid = threadIdx.x;
    if (tid < 64) {
        params[0][tid] = b1g[tid];
        params[1][tid] = b2g[tid];
        params[2][tid] = b3g[tid];
        params[3][tid] = gg[tid];
        params[4][tid] = betag[tid];
    }
    __syncthreads();
    const int wid = tid >> 6, lane = tid & 63;
    const int er = lane & 15, a = lane >> 4;
    const int ebase = (blockIdx.x * 4 + wid) * 16;
    if (ebase >= E) return;
    const int e = ebase + er;
    const int cn = edge_idx[2 * e];
    const int sn = edge_idx[2 * e + 1];
    u16* ht = htile[wid];
    const int swz = (er & 7) << 4;

    f32x4 acc[4];
#pragma unroll
    for (int m = 0; m < 4; ++m) acc[m] = 0.0f;

    // ---- layer 1: K = 192 (concat: edge_feat | node_feat[center] | node_feat[source])
#pragma unroll
    for (int s = 0; s < 6; ++s) {
        const float* src;
        if (s < 2)      src = edge_feat + (size_t)e * 64 + s * 32 + a * 8;
        else if (s < 4) src = node_feat + (size_t)cn * 64 + (s - 2) * 32 + a * 8;
        else            src = node_feat + (size_t)sn * 64 + (s - 4) * 32 + a * 8;
        bf16x8 bf = load8f_bf(src);
#pragma unroll
        for (int m = 0; m < 4; ++m) {
            bf16x8 af = *(const bf16x8*)(Pw + PK_EW1 + ((s * 4 + m) * 64 + lane) * 8);
            acc[m] = __builtin_amdgcn_mfma_f32_16x16x32_bf16(af, bf, acc[m], 0, 0, 0);
        }
    }
    // bias + relu -> htile (bf16)
#pragma unroll
    for (int m = 0; m < 4; ++m) {
        float v0 = fmaxf(acc[m][0] + params[0][16 * m + 4 * a + 0], 0.0f);
        float v1 = fmaxf(acc[m][1] + params[0][16 * m + 4 * a + 1], 0.0f);
        float v2 = fmaxf(acc[m][2] + params[0][16 * m + 4 * a + 2], 0.0f);
        float v3 = fmaxf(acc[m][3] + params[0][16 * m + 4 * a + 3], 0.0f);
        u32x2 pv;
        pv[0] = (u32)f2bf(v0) | ((u32)f2bf(v1) << 16);
        pv[1] = (u32)f2bf(v2) | ((u32)f2bf(v3) << 16);
        int boff = (er * 128 + (16 * m + 4 * a) * 2) ^ swz;
        *(u32x2*)((char*)ht + boff) = pv;
    }

    // ---- layer 2: K = 64
#pragma unroll
    for (int m = 0; m < 4; ++m) acc[m] = 0.0f;
#pragma unroll
    for (int s = 0; s < 2; ++s) {
        int boff = (er * 128 + s * 64 + a * 16) ^ swz;
        bf16x8 bf = *(const bf16x8*)((char*)ht + boff);
#pragma unroll
        for (int m = 0; m < 4; ++m) {
            bf16x8 af = *(const bf16x8*)(Pw + PK_EW2 + ((s * 4 + m) * 64 + lane) * 8);
            acc[m] = __builtin_amdgcn_mfma_f32_16x16x32_bf16(af, bf, acc[m], 0, 0, 0);
        }
    }
#pragma unroll
    for (int m = 0; m < 4; ++m) {
        float v0 = fmaxf(acc[m][0] + params[1][16 * m + 4 * a + 0], 0.0f);
        float v1 = fmaxf(acc[m][1] + params[1][16 * m + 4 * a + 1], 0.0f);
        float v2 = fmaxf(acc[m][2] + params[1][16 * m + 4 * a + 2], 0.0f);
        float v3 = fmaxf(acc[m][3] + params[1][16 * m + 4 * a + 3], 0.0f);
        u32x2 pv;
        pv[0] = (u32)f2bf(v0) | ((u32)f2bf(v1) << 16);
        pv[1] = (u32)f2bf(v2) | ((u32)f2bf(v3) << 16);
        int boff = (er * 128 + (16 * m + 4 * a) * 2) ^ swz;
        *(u32x2*)((char*)ht + boff) = pv;
    }

    // ---- layer 3: K = 64 (no relu), then LayerNorm
#pragma unroll
    for (int m = 0; m < 4; ++m) acc[m] = 0.0f;
#pragma unroll
    for (int s = 0; s < 2; ++s) {
        int boff = (er * 128 + s * 64 + a * 16) ^ swz;
        bf16x8 bf = *(const bf16x8*)((char*)ht + boff);
#pragma unroll
        for (int m = 0; m < 4; ++m) {
            bf16x8 af = *(const bf16x8*)(Pw + PK_EW3 + ((s * 4 + m) * 64 + lane) * 8);
            acc[m] = __builtin_amdgcn_mfma_f32_16x16x32_bf16(af, bf, acc[m], 0, 0, 0);
        }
    }
    float vals[16], sum = 0.0f, ssq = 0.0f;
#pragma unroll
    for (int m = 0; m < 4; ++m)
#pragma unroll
        for (int r = 0; r < 4; ++r) {
            float v = acc[m][r] + params[2][16 * m + 4 * a + r];
            vals[4 * m + r] = v; sum += v; ssq += v * v;
        }
    sum += __shfl_xor(sum, 16, 64); sum += __shfl_xor(sum, 32, 64);
    ssq += __shfl_xor(ssq, 16, 64); ssq += __shfl_xor(ssq, 32, 64);
    const float mean = sum * 0.015625f;
    const float var = ssq * 0.015625f - mean * mean;
    const float inv = rsqrtf(var + 1e-5f);
#pragma unroll
    for (int m = 0; m < 4; ++m) {
        f32x4 o;
#pragma unroll
        for (int r = 0; r < 4; ++r) {
            int f = 16 * m + 4 * a + r;
            o[r] = (vals[4 * m + r] - mean) * inv * params[3][f] + params[4][f];
        }
        *(f32x4*)(out_edge + (size_t)e * 64 + 16 * m + 4 * a) = o;
    }
}

// ---------------- node MLP + LN (register segment-sum gather) ----------------
__global__ __launch_bounds__(256) void node_mlp_kernel(
    const float* __restrict__ node_feat, const float* __restrict__ proc_edge,
    const int* __restrict__ off, const int* __restrict__ csr,
    const u16* __restrict__ Pw,
    const float* __restrict__ b1g, const float* __restrict__ b2g, const float* __restrict__ b3g,
    const float* __restrict__ gg, const float* __restrict__ betag,
    float* __restrict__ out_node, int N)
{
    __shared__ float params[5][64];
    __shared__ u16 htile[4][1024];
    const int tid = threadIdx.x;
    if (tid < 64) {
        params[0][tid] = b1g[tid];
        params[1][tid] = b2g[tid];
        params[2][tid] = b3g[tid];
        params[3][tid] = gg[tid];
        params[4][tid] = betag[tid];
    }
    __syncthreads();
    const int wid = tid >> 6, lane = tid & 63;
    const int er = lane & 15, a = lane >> 4;
    const int nbase = (blockIdx.x * 4 + wid) * 16;
    if (nbase >= N) return;
    const int n = nbase + er;
    u16* ht = htile[wid];
    const int swz = (er & 7) << 4;

    // ---- segment-sum gather into registers: feats [a*8, a*8+8) and [32+a*8, 32+a*8+8)
    f32x4 g0a = 0.0f, g0b = 0.0f, g1a = 0.0f, g1b = 0.0f;
    {
        const int beg = off[n], end = off[n + 1];
        for (int j = beg; j < end; ++j) {
            const int e = csr[j];
            const float* row = proc_edge + (size_t)e * 64;
            g0a += *(const f32x4*)(row + a * 8);
            g0b += *(const f32x4*)(row + a * 8 + 4);
            g1a += *(const f32x4*)(row + 32 + a * 8);
            g1b += *(const f32x4*)(row + 32 + a * 8 + 4);
        }
    }

    f32x4 acc[4];
#pragma unroll
    for (int m = 0; m < 4; ++m) acc[m] = 0.0f;

    // ---- layer 1: K = 128 (concat: node_feat | nodal_edge_feat)
#pragma unroll
    for (int s = 0; s < 4; ++s) {
        bf16x8 bf;
        if (s < 2)      bf = load8f_bf(node_feat + (size_t)n * 64 + s * 32 + a * 8);
        else if (s == 2) bf = cvt2bf(g0a, g0b);
        else             bf = cvt2bf(g1a, g1b);
#pragma unroll
        for (int m = 0; m < 4; ++m) {
            bf16x8 af = *(const bf16x8*)(Pw + PK_NW1 + ((s * 4 + m) * 64 + lane) * 8);
            acc[m] = __builtin_amdgcn_mfma_f32_16x16x32_bf16(af, bf, acc[m], 0, 0, 0);
        }
    }
#pragma unroll
    for (int m = 0; m < 4; ++m) {
        float v0 = fmaxf(acc[m][0] + params[0][16 * m + 4 * a + 0], 0.0f);
        float v1 = fmaxf(acc[m][1] + params[0][16 * m + 4 * a + 1], 0.0f);
        float v2 = fmaxf(acc[m][2] + params[0][16 * m + 4 * a + 2], 0.0f);
        float v3 = fmaxf(acc[m][3] + params[0][16 * m + 4 * a + 3], 0.0f);
        u32x2 pv;
        pv[0] = (u32)f2bf(v0) | ((u32)f2bf(v1) << 16);
        pv[1] = (u32)f2bf(v2) | ((u32)f2bf(v3) << 16);
        int boff = (er * 128 + (16 * m + 4 * a) * 2) ^ swz;
        *(u32x2*)((char*)ht + boff) = pv;
    }

    // ---- layer 2
#pragma unroll
    for (int m = 0; m < 4; ++m) acc[m] = 0.0f;
#pragma unroll
    for (int s = 0; s < 2; ++s) {
        int boff = (er * 128 + s * 64 + a * 16) ^ swz;
        bf16x8 bf = *(const bf16x8*)((char*)ht + boff);
#pragma unroll
        for (int m = 0; m < 4; ++m) {
            bf16x8 af = *(const bf16x8*)(Pw + PK_NW2 + ((s * 4 + m) * 64 + lane) * 8);
            acc[m] = __builtin_amdgcn_mfma_f32_16x16x32_bf16(af, bf, acc[m], 0, 0, 0);
        }
    }
#pragma unroll
    for (int m = 0; m < 4; ++m) {
        float v0 = fmaxf(acc[m][0] + params[1][16 * m + 4 * a + 0], 0.0f);
        float v1 = fmaxf(acc[m][1] + params[1][16 * m + 4 * a + 1], 0.0f);
        float v2 = fmaxf(acc[m][2] + params[1][16 * m + 4 * a + 2], 0.0f);
        float v3 = fmaxf(acc[m][3] + params[1][16 * m + 4 * a + 3], 0.0f);
        u32x2 pv;
        pv[0] = (u32)f2bf(v0) | ((u32)f2bf(v1) << 16);
        pv[1] = (u32)f2bf(v2) | ((u32)f2bf(v3) << 16);
        int boff = (er * 128 + (16 * m + 4 * a) * 2) ^ swz;
        *(u32x2*)((char*)ht + boff) = pv;
    }

    // ---- layer 3 + LN
#pragma unroll
    for (int m = 0; m < 4; ++m) acc[m] = 0.0f;
#pragma unroll
    for (int s = 0; s < 2; ++s) {
        int boff = (er * 128 + s * 64 + a * 16) ^ swz;
        bf16x8 bf = *(const bf16x8*)((char*)ht + boff);
#pragma unroll
        for (int m = 0; m < 4; ++m) {
            bf16x8 af = *(const bf16x8*)(Pw + PK_NW3 + ((s * 4 + m) * 64 + lane) * 8);
            acc[m] = __builtin_amdgcn_mfma_f32_16x16x32_bf16(af, bf, acc[m], 0, 0, 0);
        }
    }
    float vals[16], sum = 0.0f, ssq = 0.0f;
#pragma unroll
    for (int m = 0; m < 4; ++m)
#pragma unroll
        for (int r = 0; r < 4; ++r) {
            float v = acc[m][r] + params[2][16 * m + 4 * a + r];
            vals[4 * m + r] = v; sum += v; ssq += v * v;
        }
    sum += __shfl_xor(sum, 16, 64); sum += __shfl_xor(sum, 32, 64);
    ssq += __shfl_xor(ssq, 16, 64); ssq += __shfl_xor(ssq, 32, 64);
    const float mean = sum * 0.015625f;
    const float var = ssq * 0.015625f - mean * mean;
    const float inv = rsqrtf(var + 1e-5f);
#pragma unroll
    for (int m = 0; m < 4; ++m) {
        f32x4 o;
#pragma unroll
        for (int r = 0; r < 4; ++r) {
            int f = 16 * m + 4 * a + r;
            o[r] = (vals[4 * m + r] - mean) * inv * params[3][f] + params[4][f];
        }
        *(f32x4*)(out_node + (size_t)n * 64 + 16 * m + 4 * a) = o;
    }
}

extern "C" void kernel_launch(void* const* d_in, const int* in_sizes, int n_in,
                              void* d_out, int out_size, void* d_ws, size_t ws_size,
                              hipStream_t stream) {
    const float* node_feat = (const float*)d_in[0];
    const float* edge_feat = (const float*)d_in[1];
    const int* edge_idx  = (const int*)d_in[2];
    const float* eW1 = (const float*)d_in[4];
    const float* eb1 = (const float*)d_in[5];
    const float* eW2 = (const float*)d_in[6];
    const float* eb2 = (const float*)d_in[7];
    const float* eW3 = (const float*)d_in[8];
    const float* eb3 = (const float*)d_in[9];
    const float* eg  = (const float*)d_in[10];
    const float* ebt = (const float*)d_in[11];
    const float* nW1 = (const float*)d_in[12];
    const float* nb1 = (const float*)d_in[13];
    const float* nW2 = (const float*)d_in[14];
    const float* nb2 = (const float*)d_in[15];
    const float* nW3 = (const float*)d_in[16];
    const float* nb3 = (const float*)d_in[17];
    const float* ng  = (const float*)d_in[18];
    const float* nbt = (const float*)d_in[19];

    const int N = in_sizes[0] / 64;
    const int E = in_sizes[1] / 64;
    const int nparts = (N + 255) / 256;

    // ws layout
    char* w = (char*)d_ws;
    int* off      = (int*)w;                    w += (size_t)(N + 1) * 4;
    int* pos      = (int*)w;                    w += (size_t)N * 4;
    int* partials = (int*)w;                    w += 256 * 4;
    int* csr      = (int*)w;                    w += (size_t)E * 4;
    u16* Pw       = (u16*)w;

    float* out_edge = (float*)d_out;
    float* out_node = out_edge + (size_t)E * 64;

    pack_weights_kernel<<<(PK_TOTAL + 255) / 256, 256, 0, stream>>>(eW1, eW2, eW3, nW1, nW2, nW3, Pw);

    // big streaming kernel first
    const int eblocks = (E + 63) / 64;
    edge_mlp_kernel<<<eblocks, 256, 0, stream>>>(node_feat, edge_feat, edge_idx, Pw,
                                                 eb1, eb2, eb3, eg, ebt, out_edge, E);

    // CSR build (pos doubles as degree histogram)
    hipMemsetAsync(pos, 0, (size_t)N * 4, stream);
    degree_kernel<<<(E + 255) / 256, 256, 0, stream>>>(edge_idx, pos, E);
    scan_blocks_kernel<<<nparts, 256, 0, stream>>>(pos, off, partials, N);
    scan_partials_kernel<<<1, 256, 0, stream>>>(partials, nparts);
    finalize_offsets_kernel<<<(N + 255) / 256, 256, 0, stream>>>(off, pos, partials, N, E);
    fill_csr_kernel<<<(E + 255) / 256, 256, 0, stream>>>(edge_idx, pos, csr, E);

    const int nblocks = (N + 63) / 64;
    node_mlp_kernel<<<nblocks, 256, 0, stream>>>(node_feat, out_edge, off, csr, Pw,
                                                 nb1, nb2, nb3, ng, nbt, out_node, N);
}

// Round 4
// 630.136 us; speedup vs baseline: 2.2437x; 1.1110x over previous
//
#include <hip/hip_runtime.h>

typedef unsigned short u16;
typedef unsigned int u32;
typedef __attribute__((ext_vector_type(8))) __bf16 bf16x8;
typedef __attribute__((ext_vector_type(4))) float f32x4;
typedef __attribute__((ext_vector_type(2))) u32 u32x2;
typedef __attribute__((ext_vector_type(4))) u32 u32x4;

__device__ __forceinline__ u16 f2bf(float f) {
    u32 u = __float_as_uint(f);
    u = (u + 0x7FFFu + ((u >> 16) & 1u)) >> 16;
    return (u16)u;
}

// native casts -> v_cvt_pk_bf16_f32 (RNE), ~3x fewer VALU ops than bit-trick
__device__ __forceinline__ bf16x8 load8f_bf(const float* p) {
    f32x4 f0 = *(const f32x4*)p;
    f32x4 f1 = *(const f32x4*)(p + 4);
    bf16x8 r;
    r[0] = (__bf16)f0[0]; r[1] = (__bf16)f0[1]; r[2] = (__bf16)f0[2]; r[3] = (__bf16)f0[3];
    r[4] = (__bf16)f1[0]; r[5] = (__bf16)f1[1]; r[6] = (__bf16)f1[2]; r[7] = (__bf16)f1[3];
    return r;
}
__device__ __forceinline__ bf16x8 cvt2bf(f32x4 lo, f32x4 hi) {
    bf16x8 r;
    r[0] = (__bf16)lo[0]; r[1] = (__bf16)lo[1]; r[2] = (__bf16)lo[2]; r[3] = (__bf16)lo[3];
    r[4] = (__bf16)hi[0]; r[5] = (__bf16)hi[1]; r[6] = (__bf16)hi[2]; r[7] = (__bf16)hi[3];
    return r;
}
__device__ __forceinline__ u32 pk2(float x, float y) {
    __bf16 bx = (__bf16)x, by = (__bf16)y;
    return (u32)__builtin_bit_cast(u16, bx) | ((u32)__builtin_bit_cast(u16, by) << 16);
}

// packed A-fragment (W^T) layout, per layer: idx = ((s*4 + m)*64 + lane)*8 + j
// value = W[k][16*m + (lane&15)], k = s*32 + (lane>>4)*8 + j
#define PK_EW1 0
#define PK_EW2 12288
#define PK_EW3 16384
#define PK_NW1 20480
#define PK_NW2 28672
#define PK_NW3 32768
#define PK_TOTAL 36864

__global__ void pack_weights_kernel(const float* __restrict__ eW1, const float* __restrict__ eW2,
                                    const float* __restrict__ eW3, const float* __restrict__ nW1,
                                    const float* __restrict__ nW2, const float* __restrict__ nW3,
                                    u16* __restrict__ P) {
    int idx = blockIdx.x * blockDim.x + threadIdx.x;
    if (idx >= PK_TOTAL) return;
    const float* W; int base;
    if (idx < PK_EW2)      { W = eW1; base = PK_EW1; }
    else if (idx < PK_EW3) { W = eW2; base = PK_EW2; }
    else if (idx < PK_NW1) { W = eW3; base = PK_EW3; }
    else if (idx < PK_NW2) { W = nW1; base = PK_NW1; }
    else if (idx < PK_NW3) { W = nW2; base = PK_NW2; }
    else                   { W = nW3; base = PK_NW3; }
    int r = idx - base;
    int j = r & 7, lane = (r >> 3) & 63, m = (r >> 9) & 3, s = r >> 11;
    int k = s * 32 + (lane >> 4) * 8 + j;
    int col = 16 * m + (lane & 15);
    P[idx] = f2bf(W[k * 64 + col]);
}

// ---------------- CSR build ----------------
__global__ void degree_kernel(const int* __restrict__ edge_idx, int* __restrict__ deg, int E) {
    int e = blockIdx.x * blockDim.x + threadIdx.x;
    if (e < E) atomicAdd(&deg[edge_idx[2 * e]], 1);
}

__global__ void scan_blocks_kernel(const int* __restrict__ deg, int* __restrict__ off,
                                   int* __restrict__ partials, int N) {
    __shared__ int sh[256];
    const int t = threadIdx.x;
    const int g = blockIdx.x * 256 + t;
    int v = (g < N) ? deg[g] : 0;
    sh[t] = v;
    __syncthreads();
#pragma unroll
    for (int d = 1; d < 256; d <<= 1) {
        int add = (t >= d) ? sh[t - d] : 0;
        __syncthreads();
        sh[t] += add;
        __syncthreads();
    }
    if (g < N) off[g] = sh[t] - v;
    if (t == 255) partials[blockIdx.x] = sh[255];
}

__global__ void scan_partials_kernel(int* __restrict__ partials, int nparts) {
    __shared__ int sh[256];
    const int t = threadIdx.x;
    int v = (t < nparts) ? partials[t] : 0;
    sh[t] = v;
    __syncthreads();
#pragma unroll
    for (int d = 1; d < 256; d <<= 1) {
        int add = (t >= d) ? sh[t - d] : 0;
        __syncthreads();
        sh[t] += add;
        __syncthreads();
    }
    if (t < nparts) partials[t] = sh[t] - v;
}

__global__ void finalize_offsets_kernel(int* __restrict__ off, int* __restrict__ pos,
                                        const int* __restrict__ partials, int N, int E) {
    int g = blockIdx.x * blockDim.x + threadIdx.x;
    if (g < N) {
        int o = off[g] + partials[g >> 8];
        off[g] = o;
        pos[g] = o;
    }
    if (g == 0) off[N] = E;
}

__global__ void fill_csr_kernel(const int* __restrict__ edge_idx, int* __restrict__ pos,
                                int* __restrict__ csr, int E) {
    int e = blockIdx.x * blockDim.x + threadIdx.x;
    if (e < E) {
        int slot = atomicAdd(&pos[edge_idx[2 * e]], 1);
        csr[slot] = e;
    }
}

// ---------------- edge MLP + LN: 64 edges/wave (4 subtiles), shared A-frags ----------------
#define ET 4
__global__ __launch_bounds__(256) void edge_mlp_kernel(
    const float* __restrict__ node_feat, const float* __restrict__ edge_feat,
    const int* __restrict__ edge_idx, const u16* __restrict__ Pw,
    const float* __restrict__ b1g, const float* __restrict__ b2g, const float* __restrict__ b3g,
    const float* __restrict__ gg, const float* __restrict__ betag,
    float* __restrict__ out_edge, int E)
{
    __shared__ float params[5][64];
    __shared__ u16 htile[4][ET][1024];  // [wave][subtile] 16x64 bf16 tile, XOR-swizzled
    const int tid = threadIdx.x;
    if (tid < 64) {
        params[0][tid] = b1g[tid];
        params[1][tid] = b2g[tid];
        params[2][tid] = b3g[tid];
        params[3][tid] = gg[tid];
        params[4][tid] = betag[tid];
    }
    __syncthreads();
    const int wid = tid >> 6, lane = tid & 63;
    const int er = lane & 15, a = lane >> 4;
    const int ebase = (blockIdx.x * 4 + wid) * (16 * ET);
    if (ebase >= E) return;
    const int swz = (er & 7) << 4;

    int eidx[ET], cn[ET], sn[ET];
#pragma unroll
    for (int t = 0; t < ET; ++t) {
        int e = ebase + t * 16 + er;
        if (e > E - 1) e = E - 1;
        eidx[t] = e;
        int2 ii = *(const int2*)(edge_idx + 2 * e);
        cn[t] = ii.x; sn[t] = ii.y;
    }

    f32x4 acc[ET][4];
#pragma unroll
    for (int t = 0; t < ET; ++t)
#pragma unroll
        for (int m = 0; m < 4; ++m) acc[t][m] = 0.0f;

    // ---- layer 1: K = 192, 6 phases; A-frags loaded once per phase, reused x4
#pragma unroll
    for (int s = 0; s < 6; ++s) {
        bf16x8 af[4];
#pragma unroll
        for (int m = 0; m < 4; ++m)
            af[m] = *(const bf16x8*)(Pw + PK_EW1 + ((s * 4 + m) * 64 + lane) * 8);
        bf16x8 bf[ET];
#pragma unroll
        for (int t = 0; t < ET; ++t) {
            const float* src;
            if (s < 2)      src = edge_feat + (size_t)eidx[t] * 64 + s * 32 + a * 8;
            else if (s < 4) src = node_feat + (size_t)cn[t] * 64 + (s - 2) * 32 + a * 8;
            else            src = node_feat + (size_t)sn[t] * 64 + (s - 4) * 32 + a * 8;
            bf[t] = load8f_bf(src);
        }
#pragma unroll
        for (int t = 0; t < ET; ++t)
#pragma unroll
            for (int m = 0; m < 4; ++m)
                acc[t][m] = __builtin_amdgcn_mfma_f32_16x16x32_bf16(af[m], bf[t], acc[t][m], 0, 0, 0);
    }
    // bias + relu -> htile (bf16)
#pragma unroll
    for (int t = 0; t < ET; ++t) {
        u16* ht = htile[wid][t];
#pragma unroll
        for (int m = 0; m < 4; ++m) {
            float v0 = fmaxf(acc[t][m][0] + params[0][16 * m + 4 * a + 0], 0.0f);
            float v1 = fmaxf(acc[t][m][1] + params[0][16 * m + 4 * a + 1], 0.0f);
            float v2 = fmaxf(acc[t][m][2] + params[0][16 * m + 4 * a + 2], 0.0f);
            float v3 = fmaxf(acc[t][m][3] + params[0][16 * m + 4 * a + 3], 0.0f);
            u32x2 pv; pv[0] = pk2(v0, v1); pv[1] = pk2(v2, v3);
            int boff = (er * 128 + (16 * m + 4 * a) * 2) ^ swz;
            *(u32x2*)((char*)ht + boff) = pv;
        }
    }

    // ---- layer 2: K = 64
#pragma unroll
    for (int t = 0; t < ET; ++t)
#pragma unroll
        for (int m = 0; m < 4; ++m) acc[t][m] = 0.0f;
#pragma unroll
    for (int s = 0; s < 2; ++s) {
        bf16x8 af[4];
#pragma unroll
        for (int m = 0; m < 4; ++m)
            af[m] = *(const bf16x8*)(Pw + PK_EW2 + ((s * 4 + m) * 64 + lane) * 8);
#pragma unroll
        for (int t = 0; t < ET; ++t) {
            int boff = (er * 128 + s * 64 + a * 16) ^ swz;
            bf16x8 bf = *(const bf16x8*)((char*)htile[wid][t] + boff);
#pragma unroll
            for (int m = 0; m < 4; ++m)
                acc[t][m] = __builtin_amdgcn_mfma_f32_16x16x32_bf16(af[m], bf, acc[t][m], 0, 0, 0);
        }
    }
#pragma unroll
    for (int t = 0; t < ET; ++t) {
        u16* ht = htile[wid][t];
#pragma unroll
        for (int m = 0; m < 4; ++m) {
            float v0 = fmaxf(acc[t][m][0] + params[1][16 * m + 4 * a + 0], 0.0f);
            float v1 = fmaxf(acc[t][m][1] + params[1][16 * m + 4 * a + 1], 0.0f);
            float v2 = fmaxf(acc[t][m][2] + params[1][16 * m + 4 * a + 2], 0.0f);
            float v3 = fmaxf(acc[t][m][3] + params[1][16 * m + 4 * a + 3], 0.0f);
            u32x2 pv; pv[0] = pk2(v0, v1); pv[1] = pk2(v2, v3);
            int boff = (er * 128 + (16 * m + 4 * a) * 2) ^ swz;
            *(u32x2*)((char*)ht + boff) = pv;
        }
    }

    // ---- layer 3: K = 64 (no relu), then LayerNorm
#pragma unroll
    for (int t = 0; t < ET; ++t)
#pragma unroll
        for (int m = 0; m < 4; ++m) acc[t][m] = 0.0f;
#pragma unroll
    for (int s = 0; s < 2; ++s) {
        bf16x8 af[4];
#pragma unroll
        for (int m = 0; m < 4; ++m)
            af[m] = *(const bf16x8*)(Pw + PK_EW3 + ((s * 4 + m) * 64 + lane) * 8);
#pragma unroll
        for (int t = 0; t < ET; ++t) {
            int boff = (er * 128 + s * 64 + a * 16) ^ swz;
            bf16x8 bf = *(const bf16x8*)((char*)htile[wid][t] + boff);
#pragma unroll
            for (int m = 0; m < 4; ++m)
                acc[t][m] = __builtin_amdgcn_mfma_f32_16x16x32_bf16(af[m], bf, acc[t][m], 0, 0, 0);
        }
    }
#pragma unroll
    for (int t = 0; t < ET; ++t) {
        float vals[16], sum = 0.0f, ssq = 0.0f;
#pragma unroll
        for (int m = 0; m < 4; ++m)
#pragma unroll
            for (int r = 0; r < 4; ++r) {
                float v = acc[t][m][r] + params[2][16 * m + 4 * a + r];
                vals[4 * m + r] = v; sum += v; ssq += v * v;
            }
        sum += __shfl_xor(sum, 16, 64); sum += __shfl_xor(sum, 32, 64);
        ssq += __shfl_xor(ssq, 16, 64); ssq += __shfl_xor(ssq, 32, 64);
        const float mean = sum * 0.015625f;
        const float var = ssq * 0.015625f - mean * mean;
        const float inv = rsqrtf(var + 1e-5f);
        const int e = ebase + t * 16 + er;
        if (e < E) {
#pragma unroll
            for (int m = 0; m < 4; ++m) {
                f32x4 o;
#pragma unroll
                for (int r = 0; r < 4; ++r) {
                    int f = 16 * m + 4 * a + r;
                    o[r] = (vals[4 * m + r] - mean) * inv * params[3][f] + params[4][f];
                }
                *(f32x4*)(out_edge + (size_t)e * 64 + 16 * m + 4 * a) = o;
            }
        }
    }
}

// ---------------- node MLP + LN (register segment-sum gather, unrolled) ----------------
__global__ __launch_bounds__(256) void node_mlp_kernel(
    const float* __restrict__ node_feat, const float* __restrict__ proc_edge,
    const int* __restrict__ off, const int* __restrict__ csr,
    const u16* __restrict__ Pw,
    const float* __restrict__ b1g, const float* __restrict__ b2g, const float* __restrict__ b3g,
    const float* __restrict__ gg, const float* __restrict__ betag,
    float* __restrict__ out_node, int N)
{
    __shared__ float params[5][64];
    __shared__ u16 htile[4][1024];
    const int tid = threadIdx.x;
    if (tid < 64) {
        params[0][tid] = b1g[tid];
        params[1][tid] = b2g[tid];
        params[2][tid] = b3g[tid];
        params[3][tid] = gg[tid];
        params[4][tid] = betag[tid];
    }
    __syncthreads();
    const int wid = tid >> 6, lane = tid & 63;
    const int er = lane & 15, a = lane >> 4;
    const int nbase = (blockIdx.x * 4 + wid) * 16;
    if (nbase >= N) return;
    const int n = nbase + er;
    u16* ht = htile[wid];
    const int swz = (er & 7) << 4;

    // ---- segment-sum gather, unrolled x4 for load-level parallelism
    f32x4 g0a = 0.0f, g0b = 0.0f, g1a = 0.0f, g1b = 0.0f;
    {
        const int beg = off[n], end = off[n + 1];
        int j = beg;
        for (; j + 3 < end; j += 4) {
#pragma unroll
            for (int u = 0; u < 4; ++u) {
                const float* row = proc_edge + (size_t)csr[j + u] * 64;
                g0a += *(const f32x4*)(row + a * 8);
                g0b += *(const f32x4*)(row + a * 8 + 4);
                g1a += *(const f32x4*)(row + 32 + a * 8);
                g1b += *(const f32x4*)(row + 32 + a * 8 + 4);
            }
        }
        for (; j < end; ++j) {
            const float* row = proc_edge + (size_t)csr[j] * 64;
            g0a += *(const f32x4*)(row + a * 8);
            g0b += *(const f32x4*)(row + a * 8 + 4);
            g1a += *(const f32x4*)(row + 32 + a * 8);
            g1b += *(const f32x4*)(row + 32 + a * 8 + 4);
        }
    }

    f32x4 acc[4];
#pragma unroll
    for (int m = 0; m < 4; ++m) acc[m] = 0.0f;

    // ---- layer 1: K = 128
#pragma unroll
    for (int s = 0; s < 4; ++s) {
        bf16x8 af[4];
#pragma unroll
        for (int m = 0; m < 4; ++m)
            af[m] = *(const bf16x8*)(Pw + PK_NW1 + ((s * 4 + m) * 64 + lane) * 8);
        bf16x8 bf;
        if (s < 2)       bf = load8f_bf(node_feat + (size_t)n * 64 + s * 32 + a * 8);
        else if (s == 2) bf = cvt2bf(g0a, g0b);
        else             bf = cvt2bf(g1a, g1b);
#pragma unroll
        for (int m = 0; m < 4; ++m)
            acc[m] = __builtin_amdgcn_mfma_f32_16x16x32_bf16(af[m], bf, acc[m], 0, 0, 0);
    }
#pragma unroll
    for (int m = 0; m < 4; ++m) {
        float v0 = fmaxf(acc[m][0] + params[0][16 * m + 4 * a + 0], 0.0f);
        float v1 = fmaxf(acc[m][1] + params[0][16 * m + 4 * a + 1], 0.0f);
        float v2 = fmaxf(acc[m][2] + params[0][16 * m + 4 * a + 2], 0.0f);
        float v3 = fmaxf(acc[m][3] + params[0][16 * m + 4 * a + 3], 0.0f);
        u32x2 pv; pv[0] = pk2(v0, v1); pv[1] = pk2(v2, v3);
        int boff = (er * 128 + (16 * m + 4 * a) * 2) ^ swz;
        *(u32x2*)((char*)ht + boff) = pv;
    }

    // ---- layer 2
#pragma unroll
    for (int m = 0; m < 4; ++m) acc[m] = 0.0f;
#pragma unroll
    for (int s = 0; s < 2; ++s) {
        bf16x8 af[4];
#pragma unroll
        for (int m = 0; m < 4; ++m)
            af[m] = *(const bf16x8*)(Pw + PK_NW2 + ((s * 4 + m) * 64 + lane) * 8);
        int boff = (er * 128 + s * 64 + a * 16) ^ swz;
        bf16x8 bf = *(const bf16x8*)((char*)ht + boff);
#pragma unroll
        for (int m = 0; m < 4; ++m)
            acc[m] = __builtin_amdgcn_mfma_f32_16x16x32_bf16(af[m], bf, acc[m], 0, 0, 0);
    }
#pragma unroll
    for (int m = 0; m < 4; ++m) {
        float v0 = fmaxf(acc[m][0] + params[1][16 * m + 4 * a + 0], 0.0f);
        float v1 = fmaxf(acc[m][1] + params[1][16 * m + 4 * a + 1], 0.0f);
        float v2 = fmaxf(acc[m][2] + params[1][16 * m + 4 * a + 2], 0.0f);
        float v3 = fmaxf(acc[m][3] + params[1][16 * m + 4 * a + 3], 0.0f);
        u32x2 pv; pv[0] = pk2(v0, v1); pv[1] = pk2(v2, v3);
        int boff = (er * 128 + (16 * m + 4 * a) * 2) ^ swz;
        *(u32x2*)((char*)ht + boff) = pv;
    }

    // ---- layer 3 + LN
#pragma unroll
    for (int m = 0; m < 4; ++m) acc[m] = 0.0f;
#pragma unroll
    for (int s = 0; s < 2; ++s) {
        bf16x8 af[4];
#pragma unroll
        for (int m = 0; m < 4; ++m)
            af[m] = *(const bf16x8*)(Pw + PK_NW3 + ((s * 4 + m) * 64 + lane) * 8);
        int boff = (er * 128 + s * 64 + a * 16) ^ swz;
        bf16x8 bf = *(const bf16x8*)((char*)ht + boff);
#pragma unroll
        for (int m = 0; m < 4; ++m)
            acc[m] = __builtin_amdgcn_mfma_f32_16x16x32_bf16(af[m], bf, acc[m], 0, 0, 0);
    }
    float vals[16], sum = 0.0f, ssq = 0.0f;
#pragma unroll
    for (int m = 0; m < 4; ++m)
#pragma unroll
        for (int r = 0; r < 4; ++r) {
            float v = acc[m][r] + params[2][16 * m + 4 * a + r];
            vals[4 * m + r] = v; sum += v; ssq += v * v;
        }
    sum += __shfl_xor(sum, 16, 64); sum += __shfl_xor(sum, 32, 64);
    ssq += __shfl_xor(ssq, 16, 64); ssq += __shfl_xor(ssq, 32, 64);
    const float mean = sum * 0.015625f;
    const float var = ssq * 0.015625f - mean * mean;
    const float inv = rsqrtf(var + 1e-5f);
#pragma unroll
    for (int m = 0; m < 4; ++m) {
        f32x4 o;
#pragma unroll
        for (int r = 0; r < 4; ++r) {
            int f = 16 * m + 4 * a + r;
            o[r] = (vals[4 * m + r] - mean) * inv * params[3][f] + params[4][f];
        }
        *(f32x4*)(out_node + (size_t)n * 64 + 16 * m + 4 * a) = o;
    }
}

extern "C" void kernel_launch(void* const* d_in, const int* in_sizes, int n_in,
                              void* d_out, int out_size, void* d_ws, size_t ws_size,
                              hipStream_t stream) {
    const float* node_feat = (const float*)d_in[0];
    const float* edge_feat = (const float*)d_in[1];
    const int* edge_idx  = (const int*)d_in[2];
    const float* eW1 = (const float*)d_in[4];
    const float* eb1 = (const float*)d_in[5];
    const float* eW2 = (const float*)d_in[6];
    const float* eb2 = (const float*)d_in[7];
    const float* eW3 = (const float*)d_in[8];
    const float* eb3 = (const float*)d_in[9];
    const float* eg  = (const float*)d_in[10];
    const float* ebt = (const float*)d_in[11];
    const float* nW1 = (const float*)d_in[12];
    const float* nb1 = (const float*)d_in[13];
    const float* nW2 = (const float*)d_in[14];
    const float* nb2 = (const float*)d_in[15];
    const float* nW3 = (const float*)d_in[16];
    const float* nb3 = (const float*)d_in[17];
    const float* ng  = (const float*)d_in[18];
    const float* nbt = (const float*)d_in[19];

    const int N = in_sizes[0] / 64;
    const int E = in_sizes[1] / 64;
    const int nparts = (N + 255) / 256;

    // ws layout
    char* w = (char*)d_ws;
    int* off      = (int*)w;                    w += (size_t)(N + 1) * 4;
    int* pos      = (int*)w;                    w += (size_t)N * 4;
    int* partials = (int*)w;                    w += 256 * 4;
    int* csr      = (int*)w;                    w += (size_t)E * 4;
    u16* Pw       = (u16*)w;

    float* out_edge = (float*)d_out;
    float* out_node = out_edge + (size_t)E * 64;

    pack_weights_kernel<<<(PK_TOTAL + 255) / 256, 256, 0, stream>>>(eW1, eW2, eW3, nW1, nW2, nW3, Pw);

    // big streaming kernel first
    const int eblocks = (E + 255) / 256;
    edge_mlp_kernel<<<eblocks, 256, 0, stream>>>(node_feat, edge_feat, edge_idx, Pw,
                                                 eb1, eb2, eb3, eg, ebt, out_edge, E);

    // CSR build (pos doubles as degree histogram)
    hipMemsetAsync(pos, 0, (size_t)N * 4, stream);
    degree_kernel<<<(E + 255) / 256, 256, 0, stream>>>(edge_idx, pos, E);
    scan_blocks_kernel<<<nparts, 256, 0, stream>>>(pos, off, partials, N);
    scan_partials_kernel<<<1, 256, 0, stream>>>(partials, nparts);
    finalize_offsets_kernel<<<(N + 255) / 256, 256, 0, stream>>>(off, pos, partials, N, E);
    fill_csr_kernel<<<(E + 255) / 256, 256, 0, stream>>>(edge_idx, pos, csr, E);

    const int nblocks = (N + 63) / 64;
    node_mlp_kernel<<<nblocks, 256, 0, stream>>>(node_feat, out_edge, off, csr, Pw,
                                                 nb1, nb2, nb3, ng, nbt, out_node, N);
}